// Round 12
// baseline (1436.926 us; speedup 1.0000x reference)
//
#include <hip/hip_runtime.h>
#include <hip/hip_bf16.h>

#define B_  256
#define T_  256
#define F_  64
#define U_  512
#define NG_ 2048   // 4*U
#define BU_ (B_ * U_)

typedef __attribute__((ext_vector_type(8))) short short8;
typedef __attribute__((ext_vector_type(16))) float floatx16;

__device__ __forceinline__ unsigned short f2bf(float f) {
    union { float f; unsigned int u; } v; v.f = f;
    unsigned int u = v.u;
    return (unsigned short)((u + 0x7FFFu + ((u >> 16) & 1u)) >> 16);
}
__device__ __forceinline__ float bf2f(unsigned short s) {
    union { unsigned int u; float f; } v; v.u = ((unsigned int)s) << 16;
    return v.f;
}

__global__ void cast_x_kernel(const float* __restrict__ x,
                              unsigned short* __restrict__ xb, int n) {
    int i = blockIdx.x * blockDim.x + threadIdx.x;
    if (i < n) xb[i] = f2bf(x[i]);
}

// Pack weights into 32x32x16 MFMA B-fragments.
// Layout: [ug=16][tile q=4 (gate i,f,g,o)][ktile=KT][512 shorts].
__global__ void pack32_kernel(const float* __restrict__ W, const float* __restrict__ Uw,
                              unsigned short* __restrict__ dst, int KT, int KX) {
    long tid = (long)blockIdx.x * blockDim.x + threadIdx.x;
    long total = 16L * 4 * KT * 512;
    if (tid >= total) return;
    int j    = (int)(tid & 7);
    int lane = (int)((tid >> 3) & 63);
    int p512 = (int)(tid >> 9);
    int kt   = p512 % KT;
    int q    = (p512 / KT) & 3;
    int ug   = p512 / (KT * 4);
    int srcn = q * U_ + ug * 32 + (lane & 31);
    int k    = kt * 16 + (lane >> 5) * 8 + j;
    float v  = (k < KX) ? W[(long)k * NG_ + srcn] : Uw[(long)(k - KX) * NG_ + srcn];
    dst[tid] = f2bf(v);
}

// LLC-coherent ops (system scope): proven across blocks (r0/r2/r6/r9-r11).
__device__ __forceinline__ short8 llc_load(const unsigned short* p) {
    short8 r;
    asm volatile("global_load_dwordx4 %0, %1, off sc0 sc1" : "=v"(r) : "v"(p));
    return r;
}
__device__ __forceinline__ void sys_store_u32(unsigned int* p, unsigned int v) {
    asm volatile("global_store_dword %0, %1, off sc0 sc1" :: "v"(p), "v"(v) : "memory");
}
#define VMWAIT(N) asm volatile("s_waitcnt vmcnt(" #N ")" ::: "memory")
__device__ __forceinline__ void dep8(short8& x) { asm volatile("" : "+v"(x)); }

#define MFMA32(a, b, c) __builtin_amdgcn_mfma_f32_32x32x16_bf16(a, b, c, 0, 0, 0)

// LDS-only barrier (r11-proven): drain LDS ops, raw s_barrier. Global stores
// NOT drained -> h-store LLC commit overlaps next iter's load flight.
__device__ __forceinline__ void lds_barrier() {
    __builtin_amdgcn_sched_barrier(0);
    asm volatile("s_waitcnt lgkmcnt(0)" ::: "memory");
    __builtin_amdgcn_s_barrier();
    __builtin_amdgcn_sched_barrier(0);
}

// Full sentinel validation (r11-proven). Rule #18: after VMWAIT, re-pin via
// volatile dep8 BEFORE the check so it reads post-wait defs.
template<int N, int M>
__device__ __forceinline__ void wait_fresh(short8 (&d)[M], const unsigned short* b, int koff) {
    int g = 0;
    for (;;) {
        VMWAIT(0);
        __builtin_amdgcn_sched_barrier(0);
        #pragma unroll
        for (int i = 0; i < N; ++i) dep8(d[i]);   // post-wait defs
        bool bad = false;
        #pragma unroll
        for (int i = 0; i < N; ++i) {
            union { short8 s; unsigned int w[4]; } u; u.s = d[i];
            #pragma unroll
            for (int j = 0; j < 4; ++j) bad |= (u.w[j] == 0xFFFFFFFFu);
        }
        if (__ballot(bad) == 0ull) break;
        if (++g > (1 << 15)) break;   // fail visibly, never hang
        #pragma unroll
        for (int i = 0; i < N; ++i) d[i] = llc_load(b + i * 16 + koff);
    }
}

// Two-phase probe for RECURRENCE-CRITICAL waits: spin on fragment 0 only
// (16B/lane instead of N*16B -> ~8x less LLC poll traffic from the 128
// spinning consumer waves; producers' commits compete with this traffic),
// then re-issue the rest + full validation (usually passes first try).
template<int N, int M>
__device__ __forceinline__ void wait_fresh_probe(short8 (&d)[M], const unsigned short* b, int koff) {
    int g = 0;
    for (;;) {
        VMWAIT(0);
        __builtin_amdgcn_sched_barrier(0);
        dep8(d[0]);
        union { short8 s; unsigned int w[4]; } u; u.s = d[0];
        bool bad = (u.w[0] == 0xFFFFFFFFu) | (u.w[1] == 0xFFFFFFFFu)
                 | (u.w[2] == 0xFFFFFFFFu) | (u.w[3] == 0xFFFFFFFFu);
        if (__ballot(bad) == 0ull) break;
        if (++g > (1 << 15)) break;
        d[0] = llc_load(b + koff);
    }
    #pragma unroll
    for (int i = 1; i < N; ++i) d[i] = llc_load(b + i * 16 + koff);
    wait_fresh<N>(d, b, koff);
}

// Persistent 2-layer LSTM, LAYER-SPLIT PIPELINE + DATA-SENTINEL sync (r11)
// + two-phase probe + register cst/bias + b64 epilogue reads (this round).
// Blocks 0-127 = layer 1, 128-255 = layer 2; 136KB LDS -> 1 block/CU.
__global__ __launch_bounds__(512, 1) void lstm_persist(
    const unsigned short* __restrict__ xb,
    const unsigned short* __restrict__ P1,
    const unsigned short* __restrict__ P2,
    const float* __restrict__ b1, const float* __restrict__ b2,
    unsigned short* __restrict__ h1h, unsigned short* __restrict__ h2h)
{
    const int bid  = blockIdx.x;
    const bool isL1 = (bid < 128);
    const int sub  = isL1 ? bid : (bid - 128);
    const int mo   = sub & 7;        // row-slab (32 rows)
    const int ug   = sub >> 3;       // 0..15: unit-group of 32 units
    const int tid  = threadIdx.x;
    const int w    = tid >> 6;       // wave 0..7
    const int lane = tid & 63;
    const int arow = lane & 31;
    const int koff = (lane >> 5) * 8;
    const int row  = mo * 32 + arow;

    // [32][34] pad: row base 8B-aligned -> float2 reads; writes conflict-free.
    __shared__ float red[8][4][32][34];   // 8 waves x 4 gate-tiles partials

    // Per-thread epilogue state (thread <-> (row r, unit-pair u2) is FIXED):
    const int er = tid >> 4;             // epilogue row 0..31
    const int eu = (tid & 15) * 2;       // epilogue unit pair
    float cs0 = 0.f, cs1 = 0.f;          // cell state in registers
    float bg[4][2];
    {
        const float* bb = isL1 ? b1 : b2;
        #pragma unroll
        for (int q = 0; q < 4; ++q) {
            bg[q][0] = bb[q * U_ + ug * 32 + eu];
            bg[q][1] = bb[q * U_ + ug * 32 + eu + 1];
        }
    }

    if (isL1) {
        // ---------------- LAYER-1 pipeline ----------------
        // ktiles 0..35 (0-3 = x, 4-35 = h1). w0:0-4, w1:5-9, w2:10-14,
        // w3:15-19, w4:20-23, w5:24-27, w6:28-31, w7:32-35.
        const int kbase = (w < 4) ? w * 5 : 20 + (w - 4) * 4;
        const int kcnt  = (w < 4) ? 5 : 4;
        short8 wf[4][5];
        {
            const unsigned short* base = P1 + (size_t)ug * (4 * 36 * 512);
            #pragma unroll
            for (int q = 0; q < 4; ++q) {
                #pragma unroll
                for (int i = 0; i < 5; ++i) {
                    if (i < kcnt)
                        wf[q][i] = *(const short8*)(base
                            + ((size_t)(q * 36 + kbase + i) * 64 + lane) * 8);
                }
            }
        }
        __syncthreads();

        for (int k = 0; k < T_; ++k) {
            floatx16 acc[4];
            #pragma unroll
            for (int q = 0; q < 4; ++q) {
                #pragma unroll
                for (int i = 0; i < 16; ++i) acc[q][i] = 0.f;
            }

            if (w == 0) {
                // issue h load FIRST (RTT overlaps x MFMAs), then x-part
                const unsigned short* hb = h1h + (size_t)(k - 1) * BU_
                                           + (size_t)row * U_;
                short8 fa[1];
                if (k >= 1) fa[0] = llc_load(hb + koff);
                const unsigned short* xbase = xb + ((size_t)row * T_ + k) * F_;
                #pragma unroll
                for (int g = 0; g < 4; ++g) {
                    short8 a = *(const short8*)(xbase + g * 16 + koff);
                    #pragma unroll
                    for (int q = 0; q < 4; ++q) acc[q] = MFMA32(a, wf[q][g], acc[q]);
                }
                if (k >= 1) {
                    wait_fresh_probe<1>(fa, hb, koff);
                    dep8(fa[0]);
                    #pragma unroll
                    for (int q = 0; q < 4; ++q) acc[q] = MFMA32(fa[0], wf[q][4], acc[q]);
                }
            } else if (k >= 1) {
                if (w < 4) {
                    const unsigned short* hb = h1h + (size_t)(k - 1) * BU_
                                               + (size_t)row * U_ + (kbase - 4) * 16;
                    short8 fa[5];
                    #pragma unroll
                    for (int i = 0; i < 5; ++i) fa[i] = llc_load(hb + i * 16 + koff);
                    wait_fresh_probe<5>(fa, hb, koff);
                    #pragma unroll
                    for (int i = 0; i < 5; ++i) {
                        dep8(fa[i]);
                        #pragma unroll
                        for (int q = 0; q < 4; ++q) acc[q] = MFMA32(fa[i], wf[q][i], acc[q]);
                    }
                } else {
                    const unsigned short* hb = h1h + (size_t)(k - 1) * BU_
                                               + (size_t)row * U_ + (kbase - 4) * 16;
                    short8 fa[4];
                    #pragma unroll
                    for (int i = 0; i < 4; ++i) fa[i] = llc_load(hb + i * 16 + koff);
                    wait_fresh_probe<4>(fa, hb, koff);
                    #pragma unroll
                    for (int i = 0; i < 4; ++i) {
                        dep8(fa[i]);
                        #pragma unroll
                        for (int q = 0; q < 4; ++q) acc[q] = MFMA32(fa[i], wf[q][i], acc[q]);
                    }
                }
            }

            // D layout: col=lane&31 (unit), row=(r&3)+8*(r>>2)+4*(lane>>5)
            #pragma unroll
            for (int r = 0; r < 16; ++r) {
                int rr = (r & 3) + 8 * (r >> 2) + 4 * (lane >> 5);
                #pragma unroll
                for (int q = 0; q < 4; ++q) red[w][q][rr][arow] = acc[q][r];
            }
            lds_barrier();

            {   // epilogue: 512 thr = 32 rows x 16 unit-pairs; b64 reads
                float z[4][2];
                #pragma unroll
                for (int q = 0; q < 4; ++q) { z[q][0] = bg[q][0]; z[q][1] = bg[q][1]; }
                #pragma unroll
                for (int ww = 0; ww < 8; ++ww) {
                    #pragma unroll
                    for (int q = 0; q < 4; ++q) {
                        float2 v = *reinterpret_cast<const float2*>(&red[ww][q][er][eu]);
                        z[q][0] += v.x; z[q][1] += v.y;
                    }
                }
                float si0 = 1.f / (1.f + __expf(-z[0][0]));
                float sf0 = 1.f / (1.f + __expf(-z[1][0]));
                float gg0 = z[2][0] > 0.f ? z[2][0] : 0.f;
                float so0 = 1.f / (1.f + __expf(-z[3][0]));
                cs0 = sf0 * cs0 + si0 * gg0;
                float hn0 = so0 * (cs0 > 0.f ? cs0 : 0.f);
                float si1 = 1.f / (1.f + __expf(-z[0][1]));
                float sf1 = 1.f / (1.f + __expf(-z[1][1]));
                float gg1 = z[2][1] > 0.f ? z[2][1] : 0.f;
                float so1 = 1.f / (1.f + __expf(-z[3][1]));
                cs1 = sf1 * cs1 + si1 * gg1;
                float hn1 = so1 * (cs1 > 0.f ? cs1 : 0.f);
                unsigned int pk = (unsigned int)f2bf(hn0)
                                | ((unsigned int)f2bf(hn1) << 16);
                unsigned int* hp = (unsigned int*)(h1h + (size_t)k * BU_
                                   + (size_t)(mo * 32 + er) * U_ + ug * 32 + eu);
                sys_store_u32(hp, pk);   // the store IS the signal
            }
            lds_barrier();
        }
    } else {
        // ---------------- LAYER-2 pipeline ----------------
        // ktiles 0..63: 0-31 = W2 (h1[t] input), 32-63 = U2 (h2[t-1]).
        // wave w: ktiles w*8..w*8+7 (w<4: pure h1; w>=4: pure h2).
        short8 wf[4][8];
        {
            const unsigned short* base = P2 + (size_t)ug * (4 * 64 * 512);
            #pragma unroll
            for (int q = 0; q < 4; ++q) {
                #pragma unroll
                for (int i = 0; i < 8; ++i)
                    wf[q][i] = *(const short8*)(base
                        + ((size_t)(q * 64 + w * 8 + i) * 64 + lane) * 8);
            }
        }
        __syncthreads();

        for (int t = 0; t < T_; ++t) {
            floatx16 acc[4];
            #pragma unroll
            for (int q = 0; q < 4; ++q) {
                #pragma unroll
                for (int i = 0; i < 16; ++i) acc[q][i] = 0.f;
            }

            const bool isU2 = (w >= 4);
            if (!isU2 || t >= 1) {
                const unsigned short* hb = isU2
                    ? h2h + (size_t)(t - 1) * BU_ + (size_t)row * U_ + (w - 4) * 128
                    : h1h + (size_t)t * BU_       + (size_t)row * U_ + w * 128;
                short8 fb[8];
                #pragma unroll
                for (int i = 0; i < 8; ++i) fb[i] = llc_load(hb + i * 16 + koff);
                if (isU2) wait_fresh_probe<8>(fb, hb, koff);  // recurrence-critical
                else      wait_fresh<8>(fb, hb, koff);        // usually already fresh
                #pragma unroll
                for (int i = 0; i < 8; ++i) {
                    dep8(fb[i]);
                    #pragma unroll
                    for (int q = 0; q < 4; ++q) acc[q] = MFMA32(fb[i], wf[q][i], acc[q]);
                }
            }

            #pragma unroll
            for (int r = 0; r < 16; ++r) {
                int rr = (r & 3) + 8 * (r >> 2) + 4 * (lane >> 5);
                #pragma unroll
                for (int q = 0; q < 4; ++q) red[w][q][rr][arow] = acc[q][r];
            }
            lds_barrier();

            {   // epilogue
                float z[4][2];
                #pragma unroll
                for (int q = 0; q < 4; ++q) { z[q][0] = bg[q][0]; z[q][1] = bg[q][1]; }
                #pragma unroll
                for (int ww = 0; ww < 8; ++ww) {
                    #pragma unroll
                    for (int q = 0; q < 4; ++q) {
                        float2 v = *reinterpret_cast<const float2*>(&red[ww][q][er][eu]);
                        z[q][0] += v.x; z[q][1] += v.y;
                    }
                }
                float si0 = 1.f / (1.f + __expf(-z[0][0]));
                float sf0 = 1.f / (1.f + __expf(-z[1][0]));
                float gg0 = z[2][0] > 0.f ? z[2][0] : 0.f;
                float so0 = 1.f / (1.f + __expf(-z[3][0]));
                cs0 = sf0 * cs0 + si0 * gg0;
                float hn0 = so0 * (cs0 > 0.f ? cs0 : 0.f);
                float si1 = 1.f / (1.f + __expf(-z[0][1]));
                float sf1 = 1.f / (1.f + __expf(-z[1][1]));
                float gg1 = z[2][1] > 0.f ? z[2][1] : 0.f;
                float so1 = 1.f / (1.f + __expf(-z[3][1]));
                cs1 = sf1 * cs1 + si1 * gg1;
                float hn1 = so1 * (cs1 > 0.f ? cs1 : 0.f);
                unsigned int pk = (unsigned int)f2bf(hn0)
                                | ((unsigned int)f2bf(hn1) << 16);
                unsigned int* hp = (unsigned int*)(h2h + (size_t)t * BU_
                                   + (size_t)(mo * 32 + er) * U_ + ug * 32 + eu);
                sys_store_u32(hp, pk);
            }
            lds_barrier();
        }
    }
}

__global__ void dense_kernel(const unsigned short* __restrict__ h2,
                             const float* __restrict__ Wd,
                             const float* __restrict__ bd,
                             float* __restrict__ out) {
    int b = blockIdx.x;
    int lane = threadIdx.x;                  // 64 lanes
    const unsigned short* hp = h2 + (long)b * U_ + lane * 8;
    float sum = 0.f;
    #pragma unroll
    for (int j = 0; j < 8; ++j) sum += bf2f(hp[j]) * Wd[lane * 8 + j];
    #pragma unroll
    for (int off = 32; off; off >>= 1) sum += __shfl_down(sum, off);
    if (lane == 0) out[b] = 1.f / (1.f + __expf(-(sum + bd[0])));
}

extern "C" void kernel_launch(void* const* d_in, const int* in_sizes, int n_in,
                              void* d_out, int out_size, void* d_ws, size_t ws_size,
                              hipStream_t stream) {
    const float* x  = (const float*)d_in[0];
    const float* W1 = (const float*)d_in[1];
    const float* U1 = (const float*)d_in[2];
    const float* b1 = (const float*)d_in[3];
    const float* W2 = (const float*)d_in[4];
    const float* U2 = (const float*)d_in[5];
    const float* b2 = (const float*)d_in[6];
    const float* Wd = (const float*)d_in[7];
    const float* bd = (const float*)d_in[8];
    float* out = (float*)d_out;

    char* ws = (char*)d_ws;
    size_t off = 0;
    unsigned short* xb  = (unsigned short*)(ws + off); off += (size_t)B_ * T_ * F_ * 2;      // 8.39 MB
    unsigned short* P1  = (unsigned short*)(ws + off); off += (size_t)16 * 4 * 36 * 512 * 2; // 2.36 MB
    unsigned short* P2  = (unsigned short*)(ws + off); off += (size_t)16 * 4 * 64 * 512 * 2; // 4.19 MB
    unsigned short* h1h = (unsigned short*)(ws + off); off += (size_t)T_ * BU_ * 2;          // 67.1 MB
    unsigned short* h2h = (unsigned short*)(ws + off); off += (size_t)T_ * BU_ * 2;          // 67.1 MB

    // Poison both h histories (write-once buffers; 0xFFFFFFFF = not written).
    (void)hipMemsetAsync(h1h, 0xFF, (size_t)2 * T_ * BU_ * 2, stream);

    int n = B_ * T_ * F_;
    cast_x_kernel<<<(n + 255) / 256, 256, 0, stream>>>(x, xb, n);
    {
        long tot1 = 16L * 4 * 36 * 512;
        pack32_kernel<<<(int)((tot1 + 255) / 256), 256, 0, stream>>>(W1, U1, P1, 36, 64);
        long tot2 = 16L * 4 * 64 * 512;
        pack32_kernel<<<(int)((tot2 + 255) / 256), 256, 0, stream>>>(W2, U2, P2, 64, 512);
    }

    // 256 blocks x 512 thr; 136KB LDS/block -> exactly 1 block/CU, all
    // resident. Blocks 0-127 = layer-1 pipeline, 128-255 = layer-2.
    lstm_persist<<<256, 512, 0, stream>>>(xb, P1, P2, b1, b2, h1h, h2h);

    dense_kernel<<<B_, 64, 0, stream>>>(h2h + (size_t)(T_ - 1) * BU_,
                                        Wd, bd, out);
}

// Round 14
// 1286.522 us; speedup vs baseline: 1.1169x; 1.1169x over previous
//
#include <hip/hip_runtime.h>
#include <hip/hip_bf16.h>

#define B_  256
#define T_  256
#define F_  64
#define U_  512
#define NG_ 2048   // 4*U
#define BU_ (B_ * U_)

typedef __attribute__((ext_vector_type(8))) short short8;
typedef __attribute__((ext_vector_type(16))) float floatx16;

__device__ __forceinline__ unsigned short f2bf(float f) {
    union { float f; unsigned int u; } v; v.f = f;
    unsigned int u = v.u;
    return (unsigned short)((u + 0x7FFFu + ((u >> 16) & 1u)) >> 16);
}
__device__ __forceinline__ float bf2f(unsigned short s) {
    union { unsigned int u; float f; } v; v.u = ((unsigned int)s) << 16;
    return v.f;
}

__global__ void cast_x_kernel(const float* __restrict__ x,
                              unsigned short* __restrict__ xb, int n) {
    int i = blockIdx.x * blockDim.x + threadIdx.x;
    if (i < n) xb[i] = f2bf(x[i]);
}

// Pack weights into 32x32x16 MFMA B-fragments.
// Layout: [ug=16][tile q=4 (gate i,f,g,o)][ktile=KT][512 shorts].
__global__ void pack32_kernel(const float* __restrict__ W, const float* __restrict__ Uw,
                              unsigned short* __restrict__ dst, int KT, int KX) {
    long tid = (long)blockIdx.x * blockDim.x + threadIdx.x;
    long total = 16L * 4 * KT * 512;
    if (tid >= total) return;
    int j    = (int)(tid & 7);
    int lane = (int)((tid >> 3) & 63);
    int p512 = (int)(tid >> 9);
    int kt   = p512 % KT;
    int q    = (p512 / KT) & 3;
    int ug   = p512 / (KT * 4);
    int srcn = q * U_ + ug * 32 + (lane & 31);
    int k    = kt * 16 + (lane >> 5) * 8 + j;
    float v  = (k < KX) ? W[(long)k * NG_ + srcn] : Uw[(long)(k - KX) * NG_ + srcn];
    dst[tid] = f2bf(v);
}

// LLC-coherent ops (system scope): the ONLY exchange tier proven reliable on
// this chip (r0/r2/r6/r9-r11 pass; sc0-only failed 3x: r4/r7/r13 — DEAD).
__device__ __forceinline__ short8 llc_load(const unsigned short* p) {
    short8 r;
    asm volatile("global_load_dwordx4 %0, %1, off sc0 sc1" : "=v"(r) : "v"(p));
    return r;
}
__device__ __forceinline__ void sys_store_u32(unsigned int* p, unsigned int v) {
    asm volatile("global_store_dword %0, %1, off sc0 sc1" :: "v"(p), "v"(v) : "memory");
}
#define VMWAIT(N) asm volatile("s_waitcnt vmcnt(" #N ")" ::: "memory")
__device__ __forceinline__ void dep8(short8& x) { asm volatile("" : "+v"(x)); }

#define MFMA32(a, b, c) __builtin_amdgcn_mfma_f32_32x32x16_bf16(a, b, c, 0, 0, 0)

// LDS-only barrier (r11-proven): drain LDS ops, raw s_barrier. Global stores
// NOT drained -> h-store LLC commit overlaps next iter's load flight.
__device__ __forceinline__ void lds_barrier() {
    __builtin_amdgcn_sched_barrier(0);
    asm volatile("s_waitcnt lgkmcnt(0)" ::: "memory");
    __builtin_amdgcn_s_barrier();
    __builtin_amdgcn_sched_barrier(0);
}

// ---- probe gate (NEW this round) ----
// r11's wait_fresh re-reads the FULL fragment set (64-128B/lane) every spin
// round; ~2048 spinning waves => ~13TB/s of L2-bypassing poll traffic that
// saturates the LLC/fabric and inflates every RTT ~10x over the latency
// table. The probe spins on ONE 4B word per lane (lane probes fragment
// lane%N) with s_sleep pacing => ~25x less poll traffic. Purely an arrival
// estimator: the full wait_fresh validation still gates correctness.
template<int N>
__device__ __forceinline__ void probe_gate(const unsigned short* b, int koff, int lane) {
    const unsigned int* pw = (const unsigned int*)(b + (lane % N) * 16 + koff);
    int g = 0;
    for (;;) {
        unsigned int v;
        asm volatile("global_load_dword %0, %1, off sc0 sc1\n\ts_waitcnt vmcnt(0)"
                     : "=v"(v) : "v"(pw) : "memory");
        if (__ballot(v == 0xFFFFFFFFu) == 0ull) break;
        __builtin_amdgcn_s_sleep(1);
        if (++g > (1 << 16)) break;   // fail visibly, never hang
    }
}

// Full sentinel validation (r11-proven, UNCHANGED — the correctness gate).
// Every u32 word is either a written h-pair (halfwords < 0x8000 since h >= 0)
// or 0xFFFFFFFF poison. Rule #18: after VMWAIT, re-pin via volatile dep8
// BEFORE the check so it reads post-wait defs.
template<int N, int M>
__device__ __forceinline__ void wait_fresh(short8 (&d)[M], const unsigned short* b, int koff) {
    int g = 0;
    for (;;) {
        VMWAIT(0);
        __builtin_amdgcn_sched_barrier(0);
        #pragma unroll
        for (int i = 0; i < N; ++i) dep8(d[i]);   // post-wait defs
        bool bad = false;
        #pragma unroll
        for (int i = 0; i < N; ++i) {
            union { short8 s; unsigned int w[4]; } u; u.s = d[i];
            #pragma unroll
            for (int j = 0; j < 4; ++j) bad |= (u.w[j] == 0xFFFFFFFFu);
        }
        if (__ballot(bad) == 0ull) break;
        if (++g > (1 << 15)) break;   // fail visibly, never hang
        #pragma unroll
        for (int i = 0; i < N; ++i) d[i] = llc_load(b + i * 16 + koff);
    }
}

// Persistent 2-layer LSTM, LAYER-SPLIT PIPELINE + DATA-SENTINEL (r11 base,
// byte-identical except probe_gate insertions). Blocks 0-127 = layer 1,
// 128-255 = layer 2; 136KB LDS -> 1 block/CU, all 256 resident.
__global__ __launch_bounds__(512, 1) void lstm_persist(
    const unsigned short* __restrict__ xb,
    const unsigned short* __restrict__ P1,
    const unsigned short* __restrict__ P2,
    const float* __restrict__ b1, const float* __restrict__ b2,
    unsigned short* __restrict__ h1h, unsigned short* __restrict__ h2h)
{
    const int bid  = blockIdx.x;
    const bool isL1 = (bid < 128);
    const int sub  = isL1 ? bid : (bid - 128);
    const int mo   = sub & 7;        // row-slab (32 rows)
    const int ug   = sub >> 3;       // 0..15: unit-group of 32 units
    const int tid  = threadIdx.x;
    const int w    = tid >> 6;       // wave 0..7
    const int lane = tid & 63;
    const int arow = lane & 31;
    const int koff = (lane >> 5) * 8;
    const int row  = mo * 32 + arow;

    __shared__ float red[8][4][32][33];   // [33]: conflict-free (r11: 0 conflicts)
    __shared__ float cst[32][32];         // cell state (rows x units)
    __shared__ float bias_s[4][32];

    for (int i = tid; i < 1024; i += 512) cst[i >> 5][i & 31] = 0.f;
    if (tid < 128) {
        const float* bb = isL1 ? b1 : b2;
        bias_s[tid >> 5][tid & 31] = bb[(tid >> 5) * U_ + ug * 32 + (tid & 31)];
    }

    if (isL1) {
        // ---------------- LAYER-1 pipeline ----------------
        // ktiles 0..35 (0-3 = x, 4-35 = h1). w0:0-4, w1:5-9, w2:10-14,
        // w3:15-19, w4:20-23, w5:24-27, w6:28-31, w7:32-35.
        const int kbase = (w < 4) ? w * 5 : 20 + (w - 4) * 4;
        const int kcnt  = (w < 4) ? 5 : 4;
        short8 wf[4][5];
        {
            const unsigned short* base = P1 + (size_t)ug * (4 * 36 * 512);
            #pragma unroll
            for (int q = 0; q < 4; ++q) {
                #pragma unroll
                for (int i = 0; i < 5; ++i) {
                    if (i < kcnt)
                        wf[q][i] = *(const short8*)(base
                            + ((size_t)(q * 36 + kbase + i) * 64 + lane) * 8);
                }
            }
        }
        __syncthreads();

        for (int k = 0; k < T_; ++k) {
            floatx16 acc[4];
            #pragma unroll
            for (int q = 0; q < 4; ++q) {
                #pragma unroll
                for (int i = 0; i < 16; ++i) acc[q][i] = 0.f;
            }

            if (w == 0) {   // x-part (no cross-block dep; overlaps probe wait)
                const unsigned short* xbase = xb + ((size_t)row * T_ + k) * F_;
                #pragma unroll
                for (int g = 0; g < 4; ++g) {
                    short8 a = *(const short8*)(xbase + g * 16 + koff);
                    #pragma unroll
                    for (int q = 0; q < 4; ++q) acc[q] = MFMA32(a, wf[q][g], acc[q]);
                }
            }

            if (k >= 1) {   // h-part: probe (4B/lane) then load+validate
                if (w == 0) {
                    const unsigned short* hb = h1h + (size_t)(k - 1) * BU_
                                               + (size_t)row * U_;
                    probe_gate<1>(hb, koff, lane);
                    short8 fa[1];
                    fa[0] = llc_load(hb + koff);
                    wait_fresh<1>(fa, hb, koff);
                    dep8(fa[0]);
                    #pragma unroll
                    for (int q = 0; q < 4; ++q) acc[q] = MFMA32(fa[0], wf[q][4], acc[q]);
                } else if (w < 4) {
                    const unsigned short* hb = h1h + (size_t)(k - 1) * BU_
                                               + (size_t)row * U_ + (kbase - 4) * 16;
                    probe_gate<5>(hb, koff, lane);
                    short8 fa[5];
                    #pragma unroll
                    for (int i = 0; i < 5; ++i) fa[i] = llc_load(hb + i * 16 + koff);
                    wait_fresh<5>(fa, hb, koff);
                    #pragma unroll
                    for (int i = 0; i < 5; ++i) {
                        dep8(fa[i]);
                        #pragma unroll
                        for (int q = 0; q < 4; ++q) acc[q] = MFMA32(fa[i], wf[q][i], acc[q]);
                    }
                } else {
                    const unsigned short* hb = h1h + (size_t)(k - 1) * BU_
                                               + (size_t)row * U_ + (kbase - 4) * 16;
                    probe_gate<4>(hb, koff, lane);
                    short8 fa[4];
                    #pragma unroll
                    for (int i = 0; i < 4; ++i) fa[i] = llc_load(hb + i * 16 + koff);
                    wait_fresh<4>(fa, hb, koff);
                    #pragma unroll
                    for (int i = 0; i < 4; ++i) {
                        dep8(fa[i]);
                        #pragma unroll
                        for (int q = 0; q < 4; ++q) acc[q] = MFMA32(fa[i], wf[q][i], acc[q]);
                    }
                }
            }

            // D layout: col=lane&31 (unit), row=(r&3)+8*(r>>2)+4*(lane>>5)
            #pragma unroll
            for (int r = 0; r < 16; ++r) {
                int rr = (r & 3) + 8 * (r >> 2) + 4 * (lane >> 5);
                #pragma unroll
                for (int q = 0; q < 4; ++q) red[w][q][rr][arow] = acc[q][r];
            }
            lds_barrier();

            {   // epilogue: 512 thr = 32 rows x 16 unit-pairs (r11-exact)
                int r = tid >> 4, u2 = (tid & 15) * 2;
                unsigned int pk = 0;
                #pragma unroll
                for (int du = 0; du < 2; ++du) {
                    int u = u2 + du;
                    float zi = 0.f, zf = 0.f, zg = 0.f, zo = 0.f;
                    #pragma unroll
                    for (int ww = 0; ww < 8; ++ww) {
                        zi += red[ww][0][r][u];
                        zf += red[ww][1][r][u];
                        zg += red[ww][2][r][u];
                        zo += red[ww][3][r][u];
                    }
                    zi += bias_s[0][u]; zf += bias_s[1][u];
                    zg += bias_s[2][u]; zo += bias_s[3][u];
                    float si = 1.f / (1.f + __expf(-zi));
                    float sf = 1.f / (1.f + __expf(-zf));
                    float so = 1.f / (1.f + __expf(-zo));
                    float gg = zg > 0.f ? zg : 0.f;
                    float cn = sf * cst[r][u] + si * gg;
                    cst[r][u] = cn;
                    float hn = so * (cn > 0.f ? cn : 0.f);
                    pk |= ((unsigned int)f2bf(hn)) << (16 * du);
                }
                unsigned int* hp = (unsigned int*)(h1h + (size_t)k * BU_
                                   + (size_t)(mo * 32 + r) * U_ + ug * 32 + u2);
                sys_store_u32(hp, pk);   // the store IS the signal
            }
            lds_barrier();
        }
    } else {
        // ---------------- LAYER-2 pipeline ----------------
        // ktiles 0..63: 0-31 = W2 (h1[t] input), 32-63 = U2 (h2[t-1]).
        // wave w: ktiles w*8..w*8+7 (w<4: pure h1; w>=4: pure h2).
        short8 wf[4][8];
        {
            const unsigned short* base = P2 + (size_t)ug * (4 * 64 * 512);
            #pragma unroll
            for (int q = 0; q < 4; ++q) {
                #pragma unroll
                for (int i = 0; i < 8; ++i)
                    wf[q][i] = *(const short8*)(base
                        + ((size_t)(q * 64 + w * 8 + i) * 64 + lane) * 8);
            }
        }
        __syncthreads();

        for (int t = 0; t < T_; ++t) {
            floatx16 acc[4];
            #pragma unroll
            for (int q = 0; q < 4; ++q) {
                #pragma unroll
                for (int i = 0; i < 16; ++i) acc[q][i] = 0.f;
            }

            const bool isU2 = (w >= 4);
            if (!isU2 || t >= 1) {
                const unsigned short* hb = isU2
                    ? h2h + (size_t)(t - 1) * BU_ + (size_t)row * U_ + (w - 4) * 128
                    : h1h + (size_t)t * BU_       + (size_t)row * U_ + w * 128;
                probe_gate<8>(hb, koff, lane);
                short8 fb[8];
                #pragma unroll
                for (int i = 0; i < 8; ++i) fb[i] = llc_load(hb + i * 16 + koff);
                wait_fresh<8>(fb, hb, koff);
                #pragma unroll
                for (int i = 0; i < 8; ++i) {
                    dep8(fb[i]);
                    #pragma unroll
                    for (int q = 0; q < 4; ++q) acc[q] = MFMA32(fb[i], wf[q][i], acc[q]);
                }
            }

            #pragma unroll
            for (int r = 0; r < 16; ++r) {
                int rr = (r & 3) + 8 * (r >> 2) + 4 * (lane >> 5);
                #pragma unroll
                for (int q = 0; q < 4; ++q) red[w][q][rr][arow] = acc[q][r];
            }
            lds_barrier();

            {   // epilogue (r11-exact)
                int r = tid >> 4, u2 = (tid & 15) * 2;
                unsigned int pk = 0;
                #pragma unroll
                for (int du = 0; du < 2; ++du) {
                    int u = u2 + du;
                    float zi = 0.f, zf = 0.f, zg = 0.f, zo = 0.f;
                    #pragma unroll
                    for (int ww = 0; ww < 8; ++ww) {
                        zi += red[ww][0][r][u];
                        zf += red[ww][1][r][u];
                        zg += red[ww][2][r][u];
                        zo += red[ww][3][r][u];
                    }
                    zi += bias_s[0][u]; zf += bias_s[1][u];
                    zg += bias_s[2][u]; zo += bias_s[3][u];
                    float si = 1.f / (1.f + __expf(-zi));
                    float sf = 1.f / (1.f + __expf(-zf));
                    float so = 1.f / (1.f + __expf(-zo));
                    float gg = zg > 0.f ? zg : 0.f;
                    float cn = sf * cst[r][u] + si * gg;
                    cst[r][u] = cn;
                    float hn = so * (cn > 0.f ? cn : 0.f);
                    pk |= ((unsigned int)f2bf(hn)) << (16 * du);
                }
                unsigned int* hp = (unsigned int*)(h2h + (size_t)t * BU_
                                   + (size_t)(mo * 32 + r) * U_ + ug * 32 + u2);
                sys_store_u32(hp, pk);
            }
            lds_barrier();
        }
    }
}

__global__ void dense_kernel(const unsigned short* __restrict__ h2,
                             const float* __restrict__ Wd,
                             const float* __restrict__ bd,
                             float* __restrict__ out) {
    int b = blockIdx.x;
    int lane = threadIdx.x;                  // 64 lanes
    const unsigned short* hp = h2 + (long)b * U_ + lane * 8;
    float sum = 0.f;
    #pragma unroll
    for (int j = 0; j < 8; ++j) sum += bf2f(hp[j]) * Wd[lane * 8 + j];
    #pragma unroll
    for (int off = 32; off; off >>= 1) sum += __shfl_down(sum, off);
    if (lane == 0) out[b] = 1.f / (1.f + __expf(-(sum + bd[0])));
}

extern "C" void kernel_launch(void* const* d_in, const int* in_sizes, int n_in,
                              void* d_out, int out_size, void* d_ws, size_t ws_size,
                              hipStream_t stream) {
    const float* x  = (const float*)d_in[0];
    const float* W1 = (const float*)d_in[1];
    const float* U1 = (const float*)d_in[2];
    const float* b1 = (const float*)d_in[3];
    const float* W2 = (const float*)d_in[4];
    const float* U2 = (const float*)d_in[5];
    const float* b2 = (const float*)d_in[6];
    const float* Wd = (const float*)d_in[7];
    const float* bd = (const float*)d_in[8];
    float* out = (float*)d_out;

    char* ws = (char*)d_ws;
    size_t off = 0;
    unsigned short* xb  = (unsigned short*)(ws + off); off += (size_t)B_ * T_ * F_ * 2;      // 8.39 MB
    unsigned short* P1  = (unsigned short*)(ws + off); off += (size_t)16 * 4 * 36 * 512 * 2; // 2.36 MB
    unsigned short* P2  = (unsigned short*)(ws + off); off += (size_t)16 * 4 * 64 * 512 * 2; // 4.19 MB
    unsigned short* h1h = (unsigned short*)(ws + off); off += (size_t)T_ * BU_ * 2;          // 67.1 MB
    unsigned short* h2h = (unsigned short*)(ws + off); off += (size_t)T_ * BU_ * 2;          // 67.1 MB

    // Poison both h histories (write-once buffers; 0xFFFFFFFF = not written).
    (void)hipMemsetAsync(h1h, 0xFF, (size_t)2 * T_ * BU_ * 2, stream);

    int n = B_ * T_ * F_;
    cast_x_kernel<<<(n + 255) / 256, 256, 0, stream>>>(x, xb, n);
    {
        long tot1 = 16L * 4 * 36 * 512;
        pack32_kernel<<<(int)((tot1 + 255) / 256), 256, 0, stream>>>(W1, U1, P1, 36, 64);
        long tot2 = 16L * 4 * 64 * 512;
        pack32_kernel<<<(int)((tot2 + 255) / 256), 256, 0, stream>>>(W2, U2, P2, 64, 512);
    }

    // 256 blocks x 512 thr; 136KB LDS/block -> exactly 1 block/CU, all
    // resident. Blocks 0-127 = layer-1 pipeline, 128-255 = layer-2.
    lstm_persist<<<256, 512, 0, stream>>>(xb, P1, P2, b1, b2, h1h, h2h);

    dense_kernel<<<B_, 64, 0, stream>>>(h2h + (size_t)(T_ - 1) * BU_,
                                        Wd, bd, out);
}